// Round 10
// baseline (44.669 us; speedup 1.0000x reference)
//
#include <hip/hip_runtime.h>
#include <math.h>

// B=16, C=256, deeper 32x32, shallower 64x64 (fixed by reference).
// ws layout (floats): gp[16*512] | h[16*256]
// 3 dispatches: pool -> mlp layer1 -> out (inline layer2 + gate + upsample).
// Learned: intra-kernel cross-block sync costs 100x a dispatch boundary (R4/R5);
// few-block weight streaming costs more than a boundary (R6); inline layer2 (R7)
// and NT stores + prefetch (R9) win. This round: 2 slices/block latency opts.

typedef float f32x4_t __attribute__((ext_vector_type(4)));  // native vec for NT store

// ---------- 1) pool: one block per TWO (b,c) slices ----------
__global__ __launch_bounds__(256) void pool_kernel(const float* __restrict__ deeper,
                                                   const float* __restrict__ shallower,
                                                   float* __restrict__ gp) {
    const int bc0 = blockIdx.x * 2;     // slices bc0, bc0+1
    const int t = threadIdx.x;
    const float4* s0 = (const float4*)(shallower + (size_t)bc0 * 4096);
    const float4* s1 = s0 + 1024;
    const float4* d0 = (const float4*)(deeper + (size_t)bc0 * 1024);
    const float4* d1 = d0 + 256;
    // issue all 10 loads up front
    float4 a0 = s0[t], b0 = s0[t + 256], c0 = s0[t + 512], e0 = s0[t + 768];
    float4 a1 = s1[t], b1 = s1[t + 256], c1 = s1[t + 512], e1 = s1[t + 768];
    float4 f0 = d0[t], f1 = d1[t];
    float sh0 = (a0.x + a0.y + a0.z + a0.w) + (b0.x + b0.y + b0.z + b0.w)
              + (c0.x + c0.y + c0.z + c0.w) + (e0.x + e0.y + e0.z + e0.w);
    float sh1 = (a1.x + a1.y + a1.z + a1.w) + (b1.x + b1.y + b1.z + b1.w)
              + (c1.x + c1.y + c1.z + c1.w) + (e1.x + e1.y + e1.z + e1.w);
    float dp0 = f0.x + f0.y + f0.z + f0.w;
    float dp1 = f1.x + f1.y + f1.z + f1.w;
    #pragma unroll
    for (int off = 32; off > 0; off >>= 1) {
        sh0 += __shfl_down(sh0, off, 64);
        sh1 += __shfl_down(sh1, off, 64);
        dp0 += __shfl_down(dp0, off, 64);
        dp1 += __shfl_down(dp1, off, 64);
    }
    __shared__ float red[4][4];   // [kind: sh0,dp0,sh1,dp1][wave]
    if ((t & 63) == 0) {
        const int w = t >> 6;
        red[0][w] = sh0; red[1][w] = dp0; red[2][w] = sh1; red[3][w] = dp1;
    }
    __syncthreads();
    if (t < 2) {                  // thread t finalizes slice bc0+t
        const int bc = bc0 + t;
        const int bb = bc >> 8, cc = bc & 255;
        const float tsh = red[2*t][0] + red[2*t][1] + red[2*t][2] + red[2*t][3];
        const float tdp = red[2*t+1][0] + red[2*t+1][1] + red[2*t+1][2] + red[2*t+1][3];
        gp[bb * 512 + cc]       = tsh * (1.0f / 4096.0f);
        gp[bb * 512 + 256 + cc] = tdp * (1.0f / 1024.0f);
    }
}

// ---------- 2) mlp layer1: 256 blocks, one output column o per block ----------
__global__ __launch_bounds__(256) void mlp1_kernel(const float* __restrict__ gp,
                                                   const float* __restrict__ w1,
                                                   const float* __restrict__ b1,
                                                   float* __restrict__ h) {
    const int o = blockIdx.x;    // 0..255
    const int t = threadIdx.x;
    const int b = t >> 4, kc = t & 15;
    const float4* gv = (const float4*)(gp + b * 512 + kc * 32);
    const float4* wv = (const float4*)(w1 + (size_t)o * 512 + kc * 32);
    float acc = 0.0f;
    #pragma unroll
    for (int i = 0; i < 8; ++i) {
        float4 g = gv[i], w = wv[i];
        acc += g.x * w.x + g.y * w.y + g.z * w.z + g.w * w.w;
    }
    __shared__ float part[256];
    part[t] = acc;
    __syncthreads();
    if (t < 16) {
        float v = 0.0f;
        #pragma unroll
        for (int k = 0; k < 16; ++k) v += part[t * 16 + k];
        h[t * 256 + o] = fmaxf(v + b1[o], 0.0f);
    }
}

// ---------- 3) out: two slices/block; inline layer2; NT stores ----------
__global__ __launch_bounds__(256) void out_kernel(const float* __restrict__ deeper,
                                                  const float* __restrict__ shallower,
                                                  const float* __restrict__ h,
                                                  const float* __restrict__ w2,
                                                  const float* __restrict__ b2,
                                                  float* __restrict__ out) {
    const int bc0 = blockIdx.x * 2;        // slices bc0, bc0+1 (same batch b)
    const int b = bc0 >> 8;
    const int c0 = bc0 & 255, c1 = c0 + 1;
    const int t = threadIdx.x;
    __shared__ float tile0[32 * 36], tile1[32 * 36];
    __shared__ float red0[4], red1[4];
    __shared__ float sv_s[2];

    // issue order = consumption order: dot operands, deeper (LDS), shallower (last)
    const float hv  = h[b * 256 + t];
    const float wA  = w2[(size_t)c0 * 256 + t];
    const float wB  = w2[(size_t)c1 * 256 + t];
    const float4 dv0 = ((const float4*)(deeper + (size_t)bc0 * 1024))[t];
    const float4 dv1 = ((const float4*)(deeper + (size_t)bc0 * 1024))[t + 256];
    const float4* ss0 = (const float4*)(shallower + (size_t)bc0 * 4096);
    float4 sA0 = ss0[t],        sA1 = ss0[t + 256],  sA2 = ss0[t + 512],  sA3 = ss0[t + 768];
    float4 sB0 = ss0[t + 1024], sB1 = ss0[t + 1280], sB2 = ss0[t + 1536], sB3 = ss0[t + 1792];

    // sigmoid dots (share h row)
    {
        float p0 = hv * wA, p1 = hv * wB;
        #pragma unroll
        for (int off = 32; off > 0; off >>= 1) {
            p0 += __shfl_down(p0, off, 64);
            p1 += __shfl_down(p1, off, 64);
        }
        if ((t & 63) == 0) { red0[t >> 6] = p0; red1[t >> 6] = p1; }
    }
    // stage deeper tiles
    {
        const int row = t >> 3, col4 = t & 7;
        *(float4*)(tile0 + row * 36 + col4 * 4) = dv0;
        *(float4*)(tile1 + row * 36 + col4 * 4) = dv1;
    }
    __syncthreads();
    if (t < 2) {
        const float* rd = t == 0 ? red0 : red1;
        const float dot = rd[0] + rd[1] + rd[2] + rd[3] + b2[c0 + t];
        sv_s[t] = 1.0f / (1.0f + expf(-dot));
    }
    __syncthreads();
    const float s0 = sv_s[0], s1 = sv_s[1];
    f32x4_t* dst0 = (f32x4_t*)(out + (size_t)bc0 * 4096);
    f32x4_t* dst1 = dst0 + 1024;
    const float4 shA[4] = { sA0, sA1, sA2, sA3 };
    const float4 shB[4] = { sB0, sB1, sB2, sB3 };
    #pragma unroll
    for (int j = 0; j < 4; ++j) {
        const int f4 = t + j * 256;      // 0..1023, coalesced
        const int y = f4 >> 4;
        const int m = f4 & 15;
        const int yy = 2 * y - 1;
        const int yl = yy >> 2;
        const float wy = (float)(yy & 3) * 0.25f;
        const float wy1 = 1.0f - wy;
        const int y0 = yl < 0 ? 0 : yl;
        const int y1 = (yl + 1) > 31 ? 31 : (yl + 1);
        const int xa = (2 * m - 1) < 0 ? 0 : (2 * m - 1);
        const int xd = (2 * m + 2) > 31 ? 31 : (2 * m + 2);
        // slice 0
        {
            const float* r0 = tile0 + y0 * 36;
            const float* r1 = tile0 + y1 * 36;
            const float A  = r0[xa]        * wy1 + r1[xa]        * wy;
            const float Bv = r0[2 * m]     * wy1 + r1[2 * m]     * wy;
            const float Cv = r0[2 * m + 1] * wy1 + r1[2 * m + 1] * wy;
            const float D  = r0[xd]        * wy1 + r1[xd]        * wy;
            const float4 sh = shA[j];
            f32x4_t o;
            o.x = fmaf(sh.x, s0, 0.25f * A  + 0.75f * Bv);
            o.y = fmaf(sh.y, s0, 0.75f * Bv + 0.25f * Cv);
            o.z = fmaf(sh.z, s0, 0.25f * Bv + 0.75f * Cv);
            o.w = fmaf(sh.w, s0, 0.75f * Cv + 0.25f * D);
            __builtin_nontemporal_store(o, &dst0[f4]);
        }
        // slice 1
        {
            const float* r0 = tile1 + y0 * 36;
            const float* r1 = tile1 + y1 * 36;
            const float A  = r0[xa]        * wy1 + r1[xa]        * wy;
            const float Bv = r0[2 * m]     * wy1 + r1[2 * m]     * wy;
            const float Cv = r0[2 * m + 1] * wy1 + r1[2 * m + 1] * wy;
            const float D  = r0[xd]        * wy1 + r1[xd]        * wy;
            const float4 sh = shB[j];
            f32x4_t o;
            o.x = fmaf(sh.x, s1, 0.25f * A  + 0.75f * Bv);
            o.y = fmaf(sh.y, s1, 0.75f * Bv + 0.25f * Cv);
            o.z = fmaf(sh.z, s1, 0.25f * Bv + 0.75f * Cv);
            o.w = fmaf(sh.w, s1, 0.75f * Cv + 0.25f * D);
            __builtin_nontemporal_store(o, &dst1[f4]);
        }
    }
}

extern "C" void kernel_launch(void* const* d_in, const int* in_sizes, int n_in,
                              void* d_out, int out_size, void* d_ws, size_t ws_size,
                              hipStream_t stream) {
    const float* deeper    = (const float*)d_in[0];  // [16,256,32,32]
    const float* shallower = (const float*)d_in[1];  // [16,256,64,64]
    const float* w1        = (const float*)d_in[2];  // [256,512]
    const float* b1        = (const float*)d_in[3];  // [256]
    const float* w2        = (const float*)d_in[4];  // [256,256]
    const float* b2        = (const float*)d_in[5];  // [256]
    float* outp = (float*)d_out;

    float* gp = (float*)d_ws;          // 16*512
    float* h  = gp + 16 * 512;         // 16*256

    hipLaunchKernelGGL(pool_kernel, dim3(2048), dim3(256), 0, stream, deeper, shallower, gp);
    hipLaunchKernelGGL(mlp1_kernel, dim3(256), dim3(256), 0, stream, gp, w1, b1, h);
    hipLaunchKernelGGL(out_kernel, dim3(2048), dim3(256), 0, stream,
                       deeper, shallower, h, w2, b2, outp);
}